// Round 8
// baseline (956.414 us; speedup 1.0000x reference)
//
#include <hip/hip_runtime.h>
#include <hip/hip_cooperative_groups.h>

// Problem: T=2048, B=16, N=2048, binary fp32 spikes, duration=100.
// out[t,b,n] = 1 if any spike in window [t-duration+1, t], else 0.
//
// R6/R7 post-mortem: both bitmask pipelines silently fell back to the scan
// (ws_size < 16MiB; totals fit fallback+283us exactly, and R7's rewritten
// phases moved the total by noise only). This revision needs NO workspace:
// one cooperative kernel, bitmask staged in `out` itself, grid.sync()
// separating the phases (kills the WAR races that scratch-in-out has
// without grid sync):
//   P1: linear binarize  x (256MB read) -> bm u32[2048][1024] in out[0,8Mi)
//   P2: block b = t-row b: obm row = OR of bm rows [b-dur+1, b] (exact for
//       ANY dur; 100x uint4 L2-resident loads/thread) -> 4KB LDS
//   P3: block b writes its 128KB output row contiguously (bit extract +
//       float4 NT stores) -> out written as one pure linear stream
// Co-residency: 2048 blocks x 256 thr = 8 blocks/CU (=32 waves/CU), LDS
// 4KB/block, low VGPR -> fits. Falls back to the verified scan if the
// cooperative launch is rejected.

#define T_TOTAL 2048
#define M_COLS  (16 * 2048)            // 32768 floats per t-row
#define SEG_ROW (M_COLS / 256)         // 128 wave-segments per row
#define NSEG    ((long long)T_TOTAL * SEG_ROW)   // 262144
#define WPR     (M_COLS / 32)          // 1024 u32 words per row

typedef float v4f __attribute__((ext_vector_type(4)));
typedef unsigned long long u64;
typedef unsigned u32;

namespace cg = cooperative_groups;

// Bit layout contract (P1 <-> P3): segment s covers cols [256s, 256s+256);
// u64 j of segment s has bit l = (x[s*256 + 4l + j] != 0).
__global__ __launch_bounds__(256, 8) void psp_coop_kernel(
    const float* __restrict__ x,
    const int*  __restrict__ dur_p,
    float* __restrict__ out)
{
    cg::grid_group grid = cg::this_grid();
    u32* bm = (u32*)out;                       // scratch: out bytes [0, 8Mi)
    const int lane  = threadIdx.x & 63;
    const int wiblk = threadIdx.x >> 6;        // wave index in block (0..3)
    const long long nwaves = (long long)gridDim.x * 4;
    const long long wid    = (long long)blockIdx.x * 4 + wiblk;

    // ---- P1: binarize, pure linear sweep (1KB/wave float4 loads) ----
    for (long long s = wid; s < NSEG; s += nwaves) {
        v4f v = ((const v4f*)(x + s * 256))[lane];
        u64 b0 = __ballot(v.x != 0.0f);
        u64 b1 = __ballot(v.y != 0.0f);
        u64 b2 = __ballot(v.z != 0.0f);
        u64 b3 = __ballot(v.w != 0.0f);
        if (lane < 4) {
            u64 q = lane == 0 ? b0 : lane == 1 ? b1 : lane == 2 ? b2 : b3;
            ((u64*)(bm + s * 8))[lane] = q;    // 32B contiguous per segment
        }
    }
    grid.sync();

    // ---- P2: window-OR for this block's t-row -> LDS (exact, any dur) ----
    __shared__ u32 obm[WPR];                   // 4 KB
    const int b   = blockIdx.x;                // t-row owned by this block
    const int dur = dur_p[0];
    int kmax = dur - 1; if (kmax > b) kmax = b;
    uint4 acc = make_uint4(0u, 0u, 0u, 0u);
    for (int k = 0; k <= kmax; ++k) {
        const uint4 v = ((const uint4*)(bm + (long long)(b - k) * WPR))[threadIdx.x];
        acc.x |= v.x; acc.y |= v.y; acc.z |= v.z; acc.w |= v.w;
    }
    ((uint4*)obm)[threadIdx.x] = acc;
    grid.sync();   // also a block barrier: obm visible; all bm reads done
                   // before any P3 store can clobber out[0, 8Mi)

    // ---- P3: expand this row, contiguous 128KB linear NT store ----
    float* orow = out + (long long)b * M_COLS;
    for (int g = wiblk; g < SEG_ROW; g += 4) {
        const u64* qp = (const u64*)(obm + g * 8);     // uniform -> broadcast
        u64 q0 = qp[0], q1 = qp[1], q2 = qp[2], q3 = qp[3];
        v4f o;
        o.x = ((q0 >> lane) & 1ull) ? 1.0f : 0.0f;
        o.y = ((q1 >> lane) & 1ull) ? 1.0f : 0.0f;
        o.z = ((q2 >> lane) & 1ull) ? 1.0f : 0.0f;
        o.w = ((q3 >> lane) & 1ull) ? 1.0f : 0.0f;
        __builtin_nontemporal_store(o, (v4f*)(orow + g * 256) + lane);
    }
}

// ---------------- Fallback: verified single-pass scan (R0 form) ----------------
#define FCHUNK 256
__global__ __launch_bounds__(256) void psp_scan_fallback(
    const float* __restrict__ x, const int* __restrict__ dur_p,
    float* __restrict__ out)
{
    const int col = blockIdx.x * blockDim.x + threadIdx.x;
    const int t0  = blockIdx.y * FCHUNK;
    const int duration = dur_p[0];
    int last = t0 - duration;
    int tstart = t0 - duration + 1;
    if (tstart < 0) tstart = 0;
    const float* xc = x + col;
    float* oc = out + col;
    #pragma unroll 4
    for (int t = tstart; t < t0; ++t)
        if (xc[t * M_COLS] != 0.0f) last = t;
    #pragma unroll 4
    for (int t = t0; t < t0 + FCHUNK; ++t) {
        if (xc[t * M_COLS] != 0.0f) last = t;
        oc[t * M_COLS] = (t - last < duration) ? 1.0f : 0.0f;
    }
}

extern "C" void kernel_launch(void* const* d_in, const int* in_sizes, int n_in,
                              void* d_out, int out_size, void* d_ws, size_t ws_size,
                              hipStream_t stream) {
    const float* x     = (const float*)d_in[0];
    const int*   dur_p = (const int*)d_in[1];
    float*       out   = (float*)d_out;

    void* args[] = {(void*)&x, (void*)&dur_p, (void*)&out};
    hipError_t e = hipLaunchCooperativeKernel((const void*)psp_coop_kernel,
                                              dim3(T_TOTAL), dim3(256),
                                              args, 0, stream);
    if (e != hipSuccess) {
        dim3 grid(M_COLS / 256, T_TOTAL / FCHUNK);
        psp_scan_fallback<<<grid, dim3(256), 0, stream>>>(x, dur_p, out);
    }
}